// Round 8
// baseline (143.966 us; speedup 1.0000x reference)
//
#include <hip/hip_runtime.h>
#include <math.h>

#define Bq 128
#define Nn 8
#define LQ 32
#define LD 256
#define DD 128
#define EPSN 1e-12f
#define NEGV (-9999.0f)

typedef __attribute__((ext_vector_type(8))) short short8v;
typedef __attribute__((ext_vector_type(4))) int   int4v;
typedef __attribute__((ext_vector_type(4))) float f32x4;

__device__ __forceinline__ unsigned bf16_rne_hibits(float x) {
    // returns (round-to-nearest-even bf16 of x) << 16, as f32 bit pattern
    unsigned u = __float_as_uint(x);
    return (u + 0x7FFFu + ((u >> 16) & 1u)) & 0xFFFF0000u;
}

// ---------------- Kernel 1: normalize q rows, emit bf16 hi/lo planes -------
__global__ __launch_bounds__(256) void qnorm_k(const float* __restrict__ q,
                                               unsigned short* __restrict__ qh,
                                               unsigned short* __restrict__ ql) {
    int row  = blockIdx.x * 4 + (threadIdx.x >> 6);   // 4096 rows = [B][LQ]
    int lane = threadIdx.x & 63;
    size_t base = (size_t)row * DD + lane * 2;
    float2 v = *reinterpret_cast<const float2*>(q + base);
    float ss = v.x * v.x + v.y * v.y;
#pragma unroll
    for (int o = 32; o; o >>= 1) ss += __shfl_xor(ss, o);
    float inv = 1.0f / fmaxf(sqrtf(ss), EPSN);
    float x0 = v.x * inv, x1 = v.y * inv;
    unsigned h0 = bf16_rne_hibits(x0), h1 = bf16_rne_hibits(x1);
    float l0 = x0 - __uint_as_float(h0);
    float l1 = x1 - __uint_as_float(h1);
    unsigned g0 = bf16_rne_hibits(l0), g1 = bf16_rne_hibits(l1);
    *reinterpret_cast<unsigned*>(qh + base) = (h0 >> 16) | h1;
    *reinterpret_cast<unsigned*>(ql + base) = (g0 >> 16) | g1;
}

// ---------------- Kernel 2: MaxSim via MFMA ----------------
// Round-7 structure (verified): block=(tensor,n,b), wave w owns d-rows
// [w*64,w*64+64), C[32lq x 16rows] via mfma_f32_16x16x32_bf16 hi/lo split.
// Round-8 changes, occupancy-targeted (round 7: VGPR=72 -> 4 waves/SIMD cap,
// latency-bound at 29% occupancy):
//  - __launch_bounds__(256,8): force VGPR<=64 so all 8 blocks/CU go resident
//  - single-buffer d loads (no ping-pong): -8 regs; TLP hides latency
//  - truncation hi/lo split: hi = x&0xFFFF0000 (free), lo = x-hi exact,
//    lo also truncated. Error ~3*2^-16 rel (round 7 RNE had absmax~0; same
//    3-term MFMA). CVT2: ~16 -> ~10 VALU ops.
__global__ __launch_bounds__(256, 8) void maxsim_k(const float* __restrict__ d_cq,
                                                   const float* __restrict__ d_orig,
                                                   const int* __restrict__ mask,
                                                   const unsigned short* __restrict__ qh,
                                                   const unsigned short* __restrict__ ql,
                                                   float* __restrict__ scores) {
    __shared__ float wm[4][32];

    int bid = blockIdx.x;             // [0, 2048)
    int tau = bid >> 10;              // 0 = cq (student), 1 = orig (teacher)
    int nb  = bid & 1023;             // n*Bq + b
    int b   = nb & 127;
    int n   = nb >> 7;

    int tid  = threadIdx.x;
    int w    = tid >> 6;              // wave id: d-rows [w*64, w*64+64)
    int lane = tid & 63;
    int r    = lane & 15;             // B-frag col / C-frag col (local d-row)
    int g    = lane >> 4;             // k-group (8 elems each)

    const float* dbase = (tau ? d_orig : d_cq) + (size_t)nb * (LD * DD);

    // A-fragment row pointers (ushorts), fixed across nt: lq = r and 16+r
    const unsigned short* qh_r = qh + ((size_t)b * LQ + r) * DD + g * 8;
    const unsigned short* ql_r = ql + ((size_t)b * LQ + r) * DD + g * 8;

    f32x4 rm0 = {NEGV, NEGV, NEGV, NEGV};
    f32x4 rm1 = {NEGV, NEGV, NEGV, NEGV};

#define SB __builtin_amdgcn_sched_barrier(0)

#define CVT2(W, X0, X1)                                                        \
    { unsigned u0 = __float_as_uint(X0), u1 = __float_as_uint(X1);             \
      float h0 = __uint_as_float(u0 & 0xFFFF0000u);                            \
      float h1 = __uint_as_float(u1 & 0xFFFF0000u);                            \
      dhw[W] = (int)((u0 >> 16) | (u1 & 0xFFFF0000u));                         \
      float l0 = (X0) - h0, l1 = (X1) - h1;                                    \
      dlw[W] = (int)((__float_as_uint(l0) >> 16) |                             \
                     (__float_as_uint(l1) & 0xFFFF0000u));                     \
      ssq += (X0)*(X0) + (X1)*(X1); }

#define KSTEP(KS)                                                              \
    {                                                                          \
        float4 P0 = *reinterpret_cast<const float4*>(prow + (KS) * 32);        \
        float4 P1 = *reinterpret_cast<const float4*>(prow + (KS) * 32 + 4);    \
        short8v a0h = *reinterpret_cast<const short8v*>(qh_r + (KS) * 32);     \
        short8v a0l = *reinterpret_cast<const short8v*>(ql_r + (KS) * 32);     \
        short8v a1h = *reinterpret_cast<const short8v*>(qh_r + 16 * DD + (KS) * 32); \
        short8v a1l = *reinterpret_cast<const short8v*>(ql_r + 16 * DD + (KS) * 32); \
        int4v dhw, dlw;                                                        \
        CVT2(0, P0.x, P0.y) CVT2(1, P0.z, P0.w)                                \
        CVT2(2, P1.x, P1.y) CVT2(3, P1.z, P1.w)                                \
        short8v dh = __builtin_bit_cast(short8v, dhw);                         \
        short8v dl = __builtin_bit_cast(short8v, dlw);                         \
        c0 = __builtin_amdgcn_mfma_f32_16x16x32_bf16(a0h, dh, c0, 0, 0, 0);    \
        c1 = __builtin_amdgcn_mfma_f32_16x16x32_bf16(a1h, dh, c1, 0, 0, 0);    \
        c0 = __builtin_amdgcn_mfma_f32_16x16x32_bf16(a0h, dl, c0, 0, 0, 0);    \
        c1 = __builtin_amdgcn_mfma_f32_16x16x32_bf16(a1h, dl, c1, 0, 0, 0);    \
        c0 = __builtin_amdgcn_mfma_f32_16x16x32_bf16(a0l, dh, c0, 0, 0, 0);    \
        c1 = __builtin_amdgcn_mfma_f32_16x16x32_bf16(a1l, dh, c1, 0, 0, 0);    \
    }

#pragma unroll 1
    for (int nt = 0; nt < 4; ++nt) {
        int drow = w * 64 + nt * 16 + r;          // this lane's d-row (B col)
        const float* prow = dbase + (size_t)drow * DD + g * 8;

        f32x4 c0 = {0.f, 0.f, 0.f, 0.f};
        f32x4 c1 = {0.f, 0.f, 0.f, 0.f};
        float ssq = 0.0f;

        KSTEP(0); SB;
        KSTEP(1); SB;
        KSTEP(2); SB;
        KSTEP(3); SB;

        // full row ssq: lane covers k = ks*32 + g*8 + e; combine 4 g-lanes
        ssq += __shfl_xor(ssq, 16);
        ssq += __shfl_xor(ssq, 32);
        int   mk  = mask[(size_t)nb * LD + drow];
        float inv = 1.0f / fmaxf(sqrtf(ssq), EPSN);

        // C layout: col = lane&15 = local d-row; row(lq) = g*4 + i (+16 for c1)
#pragma unroll
        for (int i = 0; i < 4; ++i) {
            float s0 = mk ? c0[i] * inv : NEGV;
            float s1 = mk ? c1[i] * inv : NEGV;
            rm0[i] = fmaxf(rm0[i], s0);
            rm1[i] = fmaxf(rm1[i], s1);
        }
    }
#undef KSTEP
#undef CVT2

    // max over the wave's 64 d-rows: reduce across the 16 cols (lane&15)
#pragma unroll
    for (int i = 0; i < 4; ++i) {
#pragma unroll
        for (int o = 1; o <= 8; o <<= 1) {
            rm0[i] = fmaxf(rm0[i], __shfl_xor(rm0[i], o));
            rm1[i] = fmaxf(rm1[i], __shfl_xor(rm1[i], o));
        }
    }
    if (r == 0) {
#pragma unroll
        for (int i = 0; i < 4; ++i) {
            wm[w][g * 4 + i]      = rm0[i];
            wm[w][16 + g * 4 + i] = rm1[i];
        }
    }
    __syncthreads();

    if (tid < 32) {   // lane = lq
        float v = fmaxf(fmaxf(wm[0][tid], wm[1][tid]),
                        fmaxf(wm[2][tid], wm[3][tid]));
#pragma unroll
        for (int o = 1; o <= 16; o <<= 1) v += __shfl_xor(v, o);
        if (tid == 0)
            scores[tau * (Bq * Nn) + b * Nn + n] = v;
    }
}

// ---------------- Kernel 3: log_softmax + KL ----------------
__global__ void loss_k(const float* __restrict__ scores, float* __restrict__ out) {
    int tid = threadIdx.x;   // 128 threads, one per b
    const float* s = scores + tid * Nn;            // student (cq)
    const float* t = scores + Bq * Nn + tid * Nn;  // teacher (orig)
    float sv[Nn], tv[Nn];
#pragma unroll
    for (int n = 0; n < Nn; ++n) { sv[n] = s[n]; tv[n] = t[n]; }
    float ms = sv[0], mt = tv[0];
#pragma unroll
    for (int n = 1; n < Nn; ++n) { ms = fmaxf(ms, sv[n]); mt = fmaxf(mt, tv[n]); }
    float es = 0.0f, et = 0.0f;
#pragma unroll
    for (int n = 0; n < Nn; ++n) { es += expf(sv[n] - ms); et += expf(tv[n] - mt); }
    float lses = ms + logf(es);
    float lset = mt + logf(et);
    double kl = 0.0;
#pragma unroll
    for (int n = 0; n < Nn; ++n) {
        float lt = tv[n] - lset;
        float ls = sv[n] - lses;
        kl += (double)expf(lt) * ((double)lt - (double)ls);
    }
#pragma unroll
    for (int o = 32; o; o >>= 1) kl += __shfl_xor(kl, o);
    __shared__ double part[2];
    if ((tid & 63) == 0) part[tid >> 6] = kl;
    __syncthreads();
    if (tid == 0) out[0] = (float)((part[0] + part[1]) / (double)Bq);
}

extern "C" void kernel_launch(void* const* d_in, const int* in_sizes, int n_in,
                              void* d_out, int out_size, void* d_ws, size_t ws_size,
                              hipStream_t stream) {
    const float* q     = (const float*)d_in[0];
    const float* dcq   = (const float*)d_in[1];
    const float* dorig = (const float*)d_in[2];
    const int*   mask  = (const int*)d_in[3];
    // labels (d_in[4]) unused by the reference loss path

    unsigned short* qh = (unsigned short*)d_ws;                  // [B][32][128] bf16-hi, 1MB
    unsigned short* ql = qh + (size_t)Bq * LQ * DD;              // bf16-lo, 1MB
    float* scores      = (float*)(ql + (size_t)Bq * LQ * DD);    // [2][B][N], 8KB

    qnorm_k<<<(Bq * LQ) / 4, 256, 0, stream>>>(q, qh, ql);
    maxsim_k<<<2 * Nn * Bq, 256, 0, stream>>>(dcq, dorig, mask, qh, ql, scores);
    loss_k<<<1, 128, 0, stream>>>(scores, (float*)d_out);
}

// Round 9
// 143.827 us; speedup vs baseline: 1.0010x; 1.0010x over previous
//
#include <hip/hip_runtime.h>
#include <math.h>

#define Bq 128
#define Nn 8
#define LQ 32
#define LD 256
#define DD 128
#define EPSN 1e-12f
#define NEGV (-9999.0f)

typedef __attribute__((ext_vector_type(8))) short short8v;
typedef __attribute__((ext_vector_type(4))) int   int4v;
typedef __attribute__((ext_vector_type(4))) float f32x4;

__device__ __forceinline__ unsigned bf16_rne_hibits(float x) {
    // returns (round-to-nearest-even bf16 of x) << 16, as f32 bit pattern
    unsigned u = __float_as_uint(x);
    return (u + 0x7FFFu + ((u >> 16) & 1u)) & 0xFFFF0000u;
}

// ---------------- Kernel 1: normalize q rows, emit bf16 hi/lo planes -------
__global__ __launch_bounds__(256) void qnorm_k(const float* __restrict__ q,
                                               unsigned short* __restrict__ qh,
                                               unsigned short* __restrict__ ql) {
    int row  = blockIdx.x * 4 + (threadIdx.x >> 6);   // 4096 rows = [B][LQ]
    int lane = threadIdx.x & 63;
    size_t base = (size_t)row * DD + lane * 2;
    float2 v = *reinterpret_cast<const float2*>(q + base);
    float ss = v.x * v.x + v.y * v.y;
#pragma unroll
    for (int o = 32; o; o >>= 1) ss += __shfl_xor(ss, o);
    float inv = 1.0f / fmaxf(sqrtf(ss), EPSN);
    float x0 = v.x * inv, x1 = v.y * inv;
    unsigned h0 = bf16_rne_hibits(x0), h1 = bf16_rne_hibits(x1);
    float l0 = x0 - __uint_as_float(h0);
    float l1 = x1 - __uint_as_float(h1);
    unsigned g0 = bf16_rne_hibits(l0), g1 = bf16_rne_hibits(l1);
    *reinterpret_cast<unsigned*>(qh + base) = (h0 >> 16) | h1;
    *reinterpret_cast<unsigned*>(ql + base) = (g0 >> 16) | g1;
}

// ---------------- Kernel 2: MaxSim via MFMA ----------------
// Round-7 structure (verified math): block=(tensor,n,b), wave w owns d-rows
// [w*64,w*64+64), C[32lq x 16rows] via mfma_f32_16x16x32_bf16 hi/lo split.
// Round-9: keep __launch_bounds__(256,8) (round 8: occupancy 76% achieved)
// but make the 64-VGPR budget FEASIBLE by staggering A-frag loads:
//   - hi A-frags (8 regs) load before the 4 hi-MFMAs
//   - lo A-frags load AFTER them (SB-fenced so they can't be re-hoisted),
//     reusing the dead hi slots -> peak A-liveness 16 -> 8 regs.
// MFMA accumulation order is bit-identical to round 8 (absmax 0); only the
// load schedule changes. Round-8 failure signature was VGPR=32 + WRITE 110MB
// (allocator spill); the no-spill check this round is WRITE ~15-25MB.
__global__ __launch_bounds__(256, 8) void maxsim_k(const float* __restrict__ d_cq,
                                                   const float* __restrict__ d_orig,
                                                   const int* __restrict__ mask,
                                                   const unsigned short* __restrict__ qh,
                                                   const unsigned short* __restrict__ ql,
                                                   float* __restrict__ scores) {
    __shared__ float wm[4][32];

    int bid = blockIdx.x;             // [0, 2048)
    int tau = bid >> 10;              // 0 = cq (student), 1 = orig (teacher)
    int nb  = bid & 1023;             // n*Bq + b
    int b   = nb & 127;
    int n   = nb >> 7;

    int tid  = threadIdx.x;
    int w    = tid >> 6;              // wave id: d-rows [w*64, w*64+64)
    int lane = tid & 63;
    int r    = lane & 15;             // B-frag col / C-frag col (local d-row)
    int g    = lane >> 4;             // k-group (8 elems each)

    const float* dbase = (tau ? d_orig : d_cq) + (size_t)nb * (LD * DD);

    // A-fragment row pointers (ushorts), fixed across nt: lq = r and 16+r
    const unsigned short* qh_r = qh + ((size_t)b * LQ + r) * DD + g * 8;
    const unsigned short* ql_r = ql + ((size_t)b * LQ + r) * DD + g * 8;

    f32x4 rm0 = {NEGV, NEGV, NEGV, NEGV};
    f32x4 rm1 = {NEGV, NEGV, NEGV, NEGV};

#define SB __builtin_amdgcn_sched_barrier(0)

#define CVT2(W, X0, X1)                                                        \
    { unsigned u0 = __float_as_uint(X0), u1 = __float_as_uint(X1);             \
      float h0 = __uint_as_float(u0 & 0xFFFF0000u);                            \
      float h1 = __uint_as_float(u1 & 0xFFFF0000u);                            \
      dhw[W] = (int)((u0 >> 16) | (u1 & 0xFFFF0000u));                         \
      float l0 = (X0) - h0, l1 = (X1) - h1;                                    \
      dlw[W] = (int)((__float_as_uint(l0) >> 16) |                             \
                     (__float_as_uint(l1) & 0xFFFF0000u));                     \
      ssq += (X0)*(X0) + (X1)*(X1); }

#define KSTEP(KS)                                                              \
    {                                                                          \
        float4 P0 = *reinterpret_cast<const float4*>(prow + (KS) * 32);        \
        float4 P1 = *reinterpret_cast<const float4*>(prow + (KS) * 32 + 4);    \
        int4v dhw, dlw;                                                        \
        CVT2(0, P0.x, P0.y) CVT2(1, P0.z, P0.w)                                \
        CVT2(2, P1.x, P1.y) CVT2(3, P1.z, P1.w)                                \
        short8v dh = __builtin_bit_cast(short8v, dhw);                         \
        short8v dl = __builtin_bit_cast(short8v, dlw);                         \
        short8v a0h = *reinterpret_cast<const short8v*>(qh_r + (KS) * 32);     \
        short8v a1h = *reinterpret_cast<const short8v*>(qh_r + 16 * DD + (KS) * 32); \
        c0 = __builtin_amdgcn_mfma_f32_16x16x32_bf16(a0h, dh, c0, 0, 0, 0);    \
        c1 = __builtin_amdgcn_mfma_f32_16x16x32_bf16(a1h, dh, c1, 0, 0, 0);    \
        c0 = __builtin_amdgcn_mfma_f32_16x16x32_bf16(a0h, dl, c0, 0, 0, 0);    \
        c1 = __builtin_amdgcn_mfma_f32_16x16x32_bf16(a1h, dl, c1, 0, 0, 0);    \
        SB;                                                                    \
        short8v a0l = *reinterpret_cast<const short8v*>(ql_r + (KS) * 32);     \
        short8v a1l = *reinterpret_cast<const short8v*>(ql_r + 16 * DD + (KS) * 32); \
        c0 = __builtin_amdgcn_mfma_f32_16x16x32_bf16(a0l, dh, c0, 0, 0, 0);    \
        c1 = __builtin_amdgcn_mfma_f32_16x16x32_bf16(a1l, dh, c1, 0, 0, 0);    \
    }

#pragma unroll 1
    for (int nt = 0; nt < 4; ++nt) {
        int drow = w * 64 + nt * 16 + r;          // this lane's d-row (B col)
        const float* prow = dbase + (size_t)drow * DD + g * 8;

        f32x4 c0 = {0.f, 0.f, 0.f, 0.f};
        f32x4 c1 = {0.f, 0.f, 0.f, 0.f};
        float ssq = 0.0f;

        int mk = mask[(size_t)nb * LD + drow];    // issue early, in flight
                                                  // across the 4 ksteps
        KSTEP(0); SB;
        KSTEP(1); SB;
        KSTEP(2); SB;
        KSTEP(3); SB;

        // full row ssq: lane covers k = ks*32 + g*8 + e; combine 4 g-lanes
        ssq += __shfl_xor(ssq, 16);
        ssq += __shfl_xor(ssq, 32);
        float inv = 1.0f / fmaxf(sqrtf(ssq), EPSN);

        // C layout: col = lane&15 = local d-row; row(lq) = g*4 + i (+16 for c1)
#pragma unroll
        for (int i = 0; i < 4; ++i) {
            float s0 = mk ? c0[i] * inv : NEGV;
            float s1 = mk ? c1[i] * inv : NEGV;
            rm0[i] = fmaxf(rm0[i], s0);
            rm1[i] = fmaxf(rm1[i], s1);
        }
    }
#undef KSTEP
#undef CVT2

    // max over the wave's 64 d-rows: reduce across the 16 cols (lane&15)
#pragma unroll
    for (int i = 0; i < 4; ++i) {
#pragma unroll
        for (int o = 1; o <= 8; o <<= 1) {
            rm0[i] = fmaxf(rm0[i], __shfl_xor(rm0[i], o));
            rm1[i] = fmaxf(rm1[i], __shfl_xor(rm1[i], o));
        }
    }
    if (r == 0) {
#pragma unroll
        for (int i = 0; i < 4; ++i) {
            wm[w][g * 4 + i]      = rm0[i];
            wm[w][16 + g * 4 + i] = rm1[i];
        }
    }
    __syncthreads();

    if (tid < 32) {   // lane = lq
        float v = fmaxf(fmaxf(wm[0][tid], wm[1][tid]),
                        fmaxf(wm[2][tid], wm[3][tid]));
#pragma unroll
        for (int o = 1; o <= 16; o <<= 1) v += __shfl_xor(v, o);
        if (tid == 0)
            scores[tau * (Bq * Nn) + b * Nn + n] = v;
    }
}

// ---------------- Kernel 3: log_softmax + KL ----------------
__global__ void loss_k(const float* __restrict__ scores, float* __restrict__ out) {
    int tid = threadIdx.x;   // 128 threads, one per b
    const float* s = scores + tid * Nn;            // student (cq)
    const float* t = scores + Bq * Nn + tid * Nn;  // teacher (orig)
    float sv[Nn], tv[Nn];
#pragma unroll
    for (int n = 0; n < Nn; ++n) { sv[n] = s[n]; tv[n] = t[n]; }
    float ms = sv[0], mt = tv[0];
#pragma unroll
    for (int n = 1; n < Nn; ++n) { ms = fmaxf(ms, sv[n]); mt = fmaxf(mt, tv[n]); }
    float es = 0.0f, et = 0.0f;
#pragma unroll
    for (int n = 0; n < Nn; ++n) { es += expf(sv[n] - ms); et += expf(tv[n] - mt); }
    float lses = ms + logf(es);
    float lset = mt + logf(et);
    double kl = 0.0;
#pragma unroll
    for (int n = 0; n < Nn; ++n) {
        float lt = tv[n] - lset;
        float ls = sv[n] - lses;
        kl += (double)expf(lt) * ((double)lt - (double)ls);
    }
#pragma unroll
    for (int o = 32; o; o >>= 1) kl += __shfl_xor(kl, o);
    __shared__ double part[2];
    if ((tid & 63) == 0) part[tid >> 6] = kl;
    __syncthreads();
    if (tid == 0) out[0] = (float)((part[0] + part[1]) / (double)Bq);
}

extern "C" void kernel_launch(void* const* d_in, const int* in_sizes, int n_in,
                              void* d_out, int out_size, void* d_ws, size_t ws_size,
                              hipStream_t stream) {
    const float* q     = (const float*)d_in[0];
    const float* dcq   = (const float*)d_in[1];
    const float* dorig = (const float*)d_in[2];
    const int*   mask  = (const int*)d_in[3];
    // labels (d_in[4]) unused by the reference loss path

    unsigned short* qh = (unsigned short*)d_ws;                  // [B][32][128] bf16-hi, 1MB
    unsigned short* ql = qh + (size_t)Bq * LQ * DD;              // bf16-lo, 1MB
    float* scores      = (float*)(ql + (size_t)Bq * LQ * DD);    // [2][B][N], 8KB

    qnorm_k<<<(Bq * LQ) / 4, 256, 0, stream>>>(q, qh, ql);
    maxsim_k<<<2 * Nn * Bq, 256, 0, stream>>>(dcq, dorig, mask, qh, ql, scores);
    loss_k<<<1, 128, 0, stream>>>(scores, (float*)d_out);
}

// Round 10
// 69.264 us; speedup vs baseline: 2.0785x; 2.0765x over previous
//
#include <hip/hip_runtime.h>
#include <math.h>

#define Bq 128
#define Nn 8
#define LQ 32
#define LD 256
#define DD 128
#define EPSN 1e-12f
#define NEGV (-9999.0f)

typedef __attribute__((ext_vector_type(8))) short short8v;
typedef __attribute__((ext_vector_type(4))) int   int4v;
typedef __attribute__((ext_vector_type(4))) float f32x4;

__device__ __forceinline__ unsigned bf16_rne_hibits(float x) {
    // returns (round-to-nearest-even bf16 of x) << 16, as f32 bit pattern
    unsigned u = __float_as_uint(x);
    return (u + 0x7FFFu + ((u >> 16) & 1u)) & 0xFFFF0000u;
}

// ---------------- Kernel 1: normalize q rows, emit bf16 hi/lo planes -------
__global__ __launch_bounds__(256) void qnorm_k(const float* __restrict__ q,
                                               unsigned short* __restrict__ qh,
                                               unsigned short* __restrict__ ql) {
    int row  = blockIdx.x * 4 + (threadIdx.x >> 6);   // 4096 rows = [B][LQ]
    int lane = threadIdx.x & 63;
    size_t base = (size_t)row * DD + lane * 2;
    float2 v = *reinterpret_cast<const float2*>(q + base);
    float ss = v.x * v.x + v.y * v.y;
#pragma unroll
    for (int o = 32; o; o >>= 1) ss += __shfl_xor(ss, o);
    float inv = 1.0f / fmaxf(sqrtf(ss), EPSN);
    float x0 = v.x * inv, x1 = v.y * inv;
    unsigned h0 = bf16_rne_hibits(x0), h1 = bf16_rne_hibits(x1);
    float l0 = x0 - __uint_as_float(h0);
    float l1 = x1 - __uint_as_float(h1);
    unsigned g0 = bf16_rne_hibits(l0), g1 = bf16_rne_hibits(l1);
    *reinterpret_cast<unsigned*>(qh + base) = (h0 >> 16) | h1;
    *reinterpret_cast<unsigned*>(ql + base) = (g0 >> 16) | g1;
}

// ---------------- Kernel 2: MaxSim via MFMA ----------------
// Round-7 structure EXACTLY (72.6us, VGPR=72, no spill, absmax~0); rounds 8/9
// proved a forced 64-VGPR budget spills (needs ~72). Round-10 change is
// schedule-only, zero extra registers:
//   - d prefetch distance 1 -> 2 ksteps (load issued ~180+ cyc before use)
//   - the formerly-DEAD 4th prefetch now targets next nt's ks0/ks1, so nt
//     boundaries expose no load latency (nt==3 clamps to a dead L1 reload
//     to stay in-bounds on the last slab).
__global__ __launch_bounds__(256) void maxsim_k(const float* __restrict__ d_cq,
                                                const float* __restrict__ d_orig,
                                                const int* __restrict__ mask,
                                                const unsigned short* __restrict__ qh,
                                                const unsigned short* __restrict__ ql,
                                                float* __restrict__ scores) {
    __shared__ float wm[4][32];

    int bid = blockIdx.x;             // [0, 2048)
    int tau = bid >> 10;              // 0 = cq (student), 1 = orig (teacher)
    int nb  = bid & 1023;             // n*Bq + b
    int b   = nb & 127;
    int n   = nb >> 7;

    int tid  = threadIdx.x;
    int w    = tid >> 6;              // wave id: d-rows [w*64, w*64+64)
    int lane = tid & 63;
    int r    = lane & 15;             // B-frag col / C-frag col (local d-row)
    int g    = lane >> 4;             // k-group (8 elems each)

    const float* dbase = (tau ? d_orig : d_cq) + (size_t)nb * (LD * DD);

    // A-fragment row pointers (ushorts), fixed across nt: lq = r and 16+r
    const unsigned short* qh_r = qh + ((size_t)b * LQ + r) * DD + g * 8;
    const unsigned short* ql_r = ql + ((size_t)b * LQ + r) * DD + g * 8;

    f32x4 rm0 = {NEGV, NEGV, NEGV, NEGV};
    f32x4 rm1 = {NEGV, NEGV, NEGV, NEGV};

#define SB __builtin_amdgcn_sched_barrier(0)

#define CVT2(W, X0, X1)                                                        \
    { unsigned h0 = bf16_rne_hibits(X0), h1 = bf16_rne_hibits(X1);             \
      float lf0 = (X0) - __uint_as_float(h0);                                  \
      float lf1 = (X1) - __uint_as_float(h1);                                  \
      dhw[W] = (int)((h0 >> 16) | h1);                                         \
      dlw[W] = (int)((bf16_rne_hibits(lf0) >> 16) | bf16_rne_hibits(lf1));     \
      ssq += (X0)*(X0) + (X1)*(X1); }

// Consume buffer (C0,C1) for k-slice KS; prefetch PFOFF (floats rel. to prow)
// back into the SAME buffer; then MFMA. cvt reads the buffer before the
// reassignment, so program order guarantees WAR safety.
#define KSTEP(C0, C1, KS, PFOFF)                                               \
    {                                                                          \
        short8v a0h = *reinterpret_cast<const short8v*>(qh_r  + (KS) * 32);    \
        short8v a0l = *reinterpret_cast<const short8v*>(ql_r  + (KS) * 32);    \
        short8v a1h = *reinterpret_cast<const short8v*>(qh_r + 16 * DD + (KS) * 32); \
        short8v a1l = *reinterpret_cast<const short8v*>(ql_r + 16 * DD + (KS) * 32); \
        int4v dhw, dlw;                                                        \
        CVT2(0, C0.x, C0.y) CVT2(1, C0.z, C0.w)                                \
        CVT2(2, C1.x, C1.y) CVT2(3, C1.z, C1.w)                                \
        C0 = *reinterpret_cast<const float4*>(prow + (PFOFF));                 \
        C1 = *reinterpret_cast<const float4*>(prow + (PFOFF) + 4);             \
        short8v dh = __builtin_bit_cast(short8v, dhw);                         \
        short8v dl = __builtin_bit_cast(short8v, dlw);                         \
        c0 = __builtin_amdgcn_mfma_f32_16x16x32_bf16(a0h, dh, c0, 0, 0, 0);    \
        c1 = __builtin_amdgcn_mfma_f32_16x16x32_bf16(a1h, dh, c1, 0, 0, 0);    \
        c0 = __builtin_amdgcn_mfma_f32_16x16x32_bf16(a0h, dl, c0, 0, 0, 0);    \
        c1 = __builtin_amdgcn_mfma_f32_16x16x32_bf16(a1h, dl, c1, 0, 0, 0);    \
        c0 = __builtin_amdgcn_mfma_f32_16x16x32_bf16(a0l, dh, c0, 0, 0, 0);    \
        c1 = __builtin_amdgcn_mfma_f32_16x16x32_bf16(a1l, dh, c1, 0, 0, 0);    \
    }

    // steady-state pipeline: A holds ks0 data, B holds ks1 data at nt top
    const float* prow = dbase + (size_t)(w * 64 + r) * DD + g * 8;
    float4 A0 = *reinterpret_cast<const float4*>(prow);
    float4 A1 = *reinterpret_cast<const float4*>(prow + 4);
    float4 B0 = *reinterpret_cast<const float4*>(prow + 32);
    float4 B1 = *reinterpret_cast<const float4*>(prow + 36);

#pragma unroll 1
    for (int nt = 0; nt < 4; ++nt) {
        int drow = w * 64 + nt * 16 + r;          // this lane's d-row (B col)

        f32x4 c0 = {0.f, 0.f, 0.f, 0.f};
        f32x4 c1 = {0.f, 0.f, 0.f, 0.f};
        float ssq = 0.0f;

        int mk = mask[(size_t)nb * LD + drow];    // early, in flight over ksteps
        int nnoff = (nt < 3) ? 2048 : 0;          // next-nt stride (16 rows)

        KSTEP(A0, A1, 0, 64);          SB;        // fetch ks2 -> A
        KSTEP(B0, B1, 1, 96);          SB;        // fetch ks3 -> B
        KSTEP(A0, A1, 2, nnoff);       SB;        // fetch next-nt ks0 -> A
        KSTEP(B0, B1, 3, nnoff + 32);  SB;        // fetch next-nt ks1 -> B

        // full row ssq: lane covers k = ks*32 + g*8 + e; combine 4 g-lanes
        ssq += __shfl_xor(ssq, 16);
        ssq += __shfl_xor(ssq, 32);
        float inv = 1.0f / fmaxf(sqrtf(ssq), EPSN);

        // C layout: col = lane&15 = local d-row; row(lq) = g*4 + i (+16 for c1)
#pragma unroll
        for (int i = 0; i < 4; ++i) {
            float s0 = mk ? c0[i] * inv : NEGV;
            float s1 = mk ? c1[i] * inv : NEGV;
            rm0[i] = fmaxf(rm0[i], s0);
            rm1[i] = fmaxf(rm1[i], s1);
        }
        prow += 16 * DD;               // advance to next 16-row tile
    }
#undef KSTEP
#undef CVT2

    // max over the wave's 64 d-rows: reduce across the 16 cols (lane&15)
#pragma unroll
    for (int i = 0; i < 4; ++i) {
#pragma unroll
        for (int o = 1; o <= 8; o <<= 1) {
            rm0[i] = fmaxf(rm0[i], __shfl_xor(rm0[i], o));
            rm1[i] = fmaxf(rm1[i], __shfl_xor(rm1[i], o));
        }
    }
    if (r == 0) {
#pragma unroll
        for (int i = 0; i < 4; ++i) {
            wm[w][g * 4 + i]      = rm0[i];
            wm[w][16 + g * 4 + i] = rm1[i];
        }
    }
    __syncthreads();

    if (tid < 32) {   // lane = lq
        float v = fmaxf(fmaxf(wm[0][tid], wm[1][tid]),
                        fmaxf(wm[2][tid], wm[3][tid]));
#pragma unroll
        for (int o = 1; o <= 16; o <<= 1) v += __shfl_xor(v, o);
        if (tid == 0)
            scores[tau * (Bq * Nn) + b * Nn + n] = v;
    }
}

// ---------------- Kernel 3: log_softmax + KL ----------------
__global__ void loss_k(const float* __restrict__ scores, float* __restrict__ out) {
    int tid = threadIdx.x;   // 128 threads, one per b
    const float* s = scores + tid * Nn;            // student (cq)
    const float* t = scores + Bq * Nn + tid * Nn;  // teacher (orig)
    float sv[Nn], tv[Nn];
#pragma unroll
    for (int n = 0; n < Nn; ++n) { sv[n] = s[n]; tv[n] = t[n]; }
    float ms = sv[0], mt = tv[0];
#pragma unroll
    for (int n = 1; n < Nn; ++n) { ms = fmaxf(ms, sv[n]); mt = fmaxf(mt, tv[n]); }
    float es = 0.0f, et = 0.0f;
#pragma unroll
    for (int n = 0; n < Nn; ++n) { es += expf(sv[n] - ms); et += expf(tv[n] - mt); }
    float lses = ms + logf(es);
    float lset = mt + logf(et);
    double kl = 0.0;
#pragma unroll
    for (int n = 0; n < Nn; ++n) {
        float lt = tv[n] - lset;
        float ls = sv[n] - lses;
        kl += (double)expf(lt) * ((double)lt - (double)ls);
    }
#pragma unroll
    for (int o = 32; o; o >>= 1) kl += __shfl_xor(kl, o);
    __shared__ double part[2];
    if ((tid & 63) == 0) part[tid >> 6] = kl;
    __syncthreads();
    if (tid == 0) out[0] = (float)((part[0] + part[1]) / (double)Bq);
}

extern "C" void kernel_launch(void* const* d_in, const int* in_sizes, int n_in,
                              void* d_out, int out_size, void* d_ws, size_t ws_size,
                              hipStream_t stream) {
    const float* q     = (const float*)d_in[0];
    const float* dcq   = (const float*)d_in[1];
    const float* dorig = (const float*)d_in[2];
    const int*   mask  = (const int*)d_in[3];
    // labels (d_in[4]) unused by the reference loss path

    unsigned short* qh = (unsigned short*)d_ws;                  // [B][32][128] bf16-hi, 1MB
    unsigned short* ql = qh + (size_t)Bq * LQ * DD;              // bf16-lo, 1MB
    float* scores      = (float*)(ql + (size_t)Bq * LQ * DD);    // [2][B][N], 8KB

    qnorm_k<<<(Bq * LQ) / 4, 256, 0, stream>>>(q, qh, ql);
    maxsim_k<<<2 * Nn * Bq, 256, 0, stream>>>(dcq, dorig, mask, qh, ql, scores);
    loss_k<<<1, 128, 0, stream>>>(scores, (float*)d_out);
}

// Round 11
// 65.561 us; speedup vs baseline: 2.1959x; 1.0565x over previous
//
#include <hip/hip_runtime.h>
#include <math.h>

#define Bq 128
#define Nn 8
#define LQ 32
#define LD 256
#define DD 128
#define EPSN 1e-12f
#define NEGV (-9999.0f)

typedef __attribute__((ext_vector_type(8))) short short8v;
typedef __attribute__((ext_vector_type(4))) int   int4v;
typedef __attribute__((ext_vector_type(4))) float f32x4;

__device__ __forceinline__ unsigned bf16_rne_hibits(float x) {
    // returns (round-to-nearest-even bf16 of x) << 16, as f32 bit pattern
    unsigned u = __float_as_uint(x);
    return (u + 0x7FFFu + ((u >> 16) & 1u)) & 0xFFFF0000u;
}

// ---------------- Kernel 1: normalize q rows, emit bf16 hi/lo planes -------
__global__ __launch_bounds__(256) void qnorm_k(const float* __restrict__ q,
                                               unsigned short* __restrict__ qh,
                                               unsigned short* __restrict__ ql) {
    int row  = blockIdx.x * 4 + (threadIdx.x >> 6);   // 4096 rows = [B][LQ]
    int lane = threadIdx.x & 63;
    size_t base = (size_t)row * DD + lane * 2;
    float2 v = *reinterpret_cast<const float2*>(q + base);
    float ss = v.x * v.x + v.y * v.y;
#pragma unroll
    for (int o = 32; o; o >>= 1) ss += __shfl_xor(ss, o);
    float inv = 1.0f / fmaxf(sqrtf(ss), EPSN);
    float x0 = v.x * inv, x1 = v.y * inv;
    unsigned h0 = bf16_rne_hibits(x0), h1 = bf16_rne_hibits(x1);
    float l0 = x0 - __uint_as_float(h0);
    float l1 = x1 - __uint_as_float(h1);
    unsigned g0 = bf16_rne_hibits(l0), g1 = bf16_rne_hibits(l1);
    *reinterpret_cast<unsigned*>(qh + base) = (h0 >> 16) | h1;
    *reinterpret_cast<unsigned*>(ql + base) = (g0 >> 16) | g1;
}

// ---------------- Kernel 2: MaxSim via MFMA, dual-tensor streams ----------
// Round-7/10 verified math (C layout, hi/lo split, B-frag station map).
// Round-11: block = one (n,b) handling BOTH tensors as two interleaved
// d-streams per wave that SHARE the A-fragments (same b -> same q):
//   - grid 1024 = exactly 4 blocks/CU resident (single round, no tail)
//   - 4 A-loads feed 12 MFMAs (2x amortization vs round 10)
//   - 2x d-load MLP per wave; A-load -> first MFMA distance ~2 cvt blocks
// Register budget (counted): A16 + P32 + dhw/dlw16 + c16 + rm16 + misc~18
// = ~112 < 128 -> stays in 4-wave/SIMD band. Spill check: WRITE ~<30MB.
__global__ __launch_bounds__(256) void maxsim_k(const float* __restrict__ d_cq,
                                                const float* __restrict__ d_orig,
                                                const int* __restrict__ mask,
                                                const unsigned short* __restrict__ qh,
                                                const unsigned short* __restrict__ ql,
                                                float* __restrict__ scores) {
    __shared__ float wma[4][32];
    __shared__ float wmb[4][32];

    int nb = blockIdx.x;              // n*Bq + b, [0,1024)
    int b  = nb & 127;
    int n  = nb >> 7;

    int tid  = threadIdx.x;
    int w    = tid >> 6;              // wave id: d-rows [w*64, w*64+64)
    int lane = tid & 63;
    int r    = lane & 15;             // B-frag col / C col (local d-row)
    int g    = lane >> 4;             // k-group (8 elems each)

    // A-fragment row pointers, fixed: lq = r and 16+r
    const unsigned short* qh_r = qh + ((size_t)b * LQ + r) * DD + g * 8;
    const unsigned short* ql_r = ql + ((size_t)b * LQ + r) * DD + g * 8;

    f32x4 rm0a = {NEGV, NEGV, NEGV, NEGV}, rm1a = {NEGV, NEGV, NEGV, NEGV};
    f32x4 rm0b = {NEGV, NEGV, NEGV, NEGV}, rm1b = {NEGV, NEGV, NEGV, NEGV};

#define SB __builtin_amdgcn_sched_barrier(0)

#define CVT2(DH, DL, W, X0, X1, SSQ)                                           \
    { unsigned h0 = bf16_rne_hibits(X0), h1 = bf16_rne_hibits(X1);             \
      float lf0 = (X0) - __uint_as_float(h0);                                  \
      float lf1 = (X1) - __uint_as_float(h1);                                  \
      DH[W] = (int)((h0 >> 16) | h1);                                          \
      DL[W] = (int)((bf16_rne_hibits(lf0) >> 16) | bf16_rne_hibits(lf1));      \
      SSQ += (X0)*(X0) + (X1)*(X1); }

// One k-slice for both streams. Consumes (CA0,CA1) from d_cq stream and
// (CB0,CB1) from d_orig stream; prefetches PFOFF into the same buffers
// (WAR-safe: cvt reads precede reassignment in program order); A-frags are
// loaded at the top so both cvt blocks separate them from the MFMAs.
#define KSTEP(CA0, CA1, CB0, CB1, KS, PFOFF)                                   \
    {                                                                          \
        short8v a0h = *reinterpret_cast<const short8v*>(qh_r + (KS) * 32);     \
        short8v a0l = *reinterpret_cast<const short8v*>(ql_r + (KS) * 32);     \
        short8v a1h = *reinterpret_cast<const short8v*>(qh_r + 16 * DD + (KS) * 32); \
        short8v a1l = *reinterpret_cast<const short8v*>(ql_r + 16 * DD + (KS) * 32); \
        int4v dhwa, dlwa, dhwb, dlwb;                                          \
        CVT2(dhwa, dlwa, 0, CA0.x, CA0.y, ssqa)                                \
        CVT2(dhwa, dlwa, 1, CA0.z, CA0.w, ssqa)                                \
        CVT2(dhwa, dlwa, 2, CA1.x, CA1.y, ssqa)                                \
        CVT2(dhwa, dlwa, 3, CA1.z, CA1.w, ssqa)                                \
        CA0 = *reinterpret_cast<const float4*>(prow_a + (PFOFF));              \
        CA1 = *reinterpret_cast<const float4*>(prow_a + (PFOFF) + 4);          \
        CVT2(dhwb, dlwb, 0, CB0.x, CB0.y, ssqb)                                \
        CVT2(dhwb, dlwb, 1, CB0.z, CB0.w, ssqb)                                \
        CVT2(dhwb, dlwb, 2, CB1.x, CB1.y, ssqb)                                \
        CVT2(dhwb, dlwb, 3, CB1.z, CB1.w, ssqb)                                \
        CB0 = *reinterpret_cast<const float4*>(prow_b + (PFOFF));              \
        CB1 = *reinterpret_cast<const float4*>(prow_b + (PFOFF) + 4);          \
        short8v dha = __builtin_bit_cast(short8v, dhwa);                       \
        short8v dla = __builtin_bit_cast(short8v, dlwa);                       \
        c0a = __builtin_amdgcn_mfma_f32_16x16x32_bf16(a0h, dha, c0a, 0, 0, 0); \
        c1a = __builtin_amdgcn_mfma_f32_16x16x32_bf16(a1h, dha, c1a, 0, 0, 0); \
        c0a = __builtin_amdgcn_mfma_f32_16x16x32_bf16(a0h, dla, c0a, 0, 0, 0); \
        c1a = __builtin_amdgcn_mfma_f32_16x16x32_bf16(a1h, dla, c1a, 0, 0, 0); \
        c0a = __builtin_amdgcn_mfma_f32_16x16x32_bf16(a0l, dha, c0a, 0, 0, 0); \
        c1a = __builtin_amdgcn_mfma_f32_16x16x32_bf16(a1l, dha, c1a, 0, 0, 0); \
        short8v dhb = __builtin_bit_cast(short8v, dhwb);                       \
        short8v dlb = __builtin_bit_cast(short8v, dlwb);                       \
        c0b = __builtin_amdgcn_mfma_f32_16x16x32_bf16(a0h, dhb, c0b, 0, 0, 0); \
        c1b = __builtin_amdgcn_mfma_f32_16x16x32_bf16(a1h, dhb, c1b, 0, 0, 0); \
        c0b = __builtin_amdgcn_mfma_f32_16x16x32_bf16(a0h, dlb, c0b, 0, 0, 0); \
        c1b = __builtin_amdgcn_mfma_f32_16x16x32_bf16(a1h, dlb, c1b, 0, 0, 0); \
        c0b = __builtin_amdgcn_mfma_f32_16x16x32_bf16(a0l, dhb, c0b, 0, 0, 0); \
        c1b = __builtin_amdgcn_mfma_f32_16x16x32_bf16(a1l, dhb, c1b, 0, 0, 0); \
    }

    // per-lane row pointers for the two streams (same geometry, two tensors)
    const float* prow_a = d_cq   + (size_t)nb * (LD * DD) + (size_t)(w * 64 + r) * DD + g * 8;
    const float* prow_b = d_orig + (size_t)nb * (LD * DD) + (size_t)(w * 64 + r) * DD + g * 8;

    // steady-state: X holds ks0, Y holds ks1 at nt-loop top (both streams)
    float4 Xa0 = *reinterpret_cast<const float4*>(prow_a);
    float4 Xa1 = *reinterpret_cast<const float4*>(prow_a + 4);
    float4 Xb0 = *reinterpret_cast<const float4*>(prow_b);
    float4 Xb1 = *reinterpret_cast<const float4*>(prow_b + 4);
    float4 Ya0 = *reinterpret_cast<const float4*>(prow_a + 32);
    float4 Ya1 = *reinterpret_cast<const float4*>(prow_a + 36);
    float4 Yb0 = *reinterpret_cast<const float4*>(prow_b + 32);
    float4 Yb1 = *reinterpret_cast<const float4*>(prow_b + 36);

#pragma unroll 1
    for (int nt = 0; nt < 4; ++nt) {
        int drow = w * 64 + nt * 16 + r;

        f32x4 c0a = {0.f, 0.f, 0.f, 0.f}, c1a = {0.f, 0.f, 0.f, 0.f};
        f32x4 c0b = {0.f, 0.f, 0.f, 0.f}, c1b = {0.f, 0.f, 0.f, 0.f};
        float ssqa = 0.0f, ssqb = 0.0f;

        int mk = mask[(size_t)nb * LD + drow];    // shared by both tensors
        int nnoff = (nt < 3) ? 2048 : 0;          // next-nt (16 rows) or clamp

        KSTEP(Xa0, Xa1, Xb0, Xb1, 0, 64);         SB;   // fetch ks2 -> X
        KSTEP(Ya0, Ya1, Yb0, Yb1, 1, 96);         SB;   // fetch ks3 -> Y
        KSTEP(Xa0, Xa1, Xb0, Xb1, 2, nnoff);      SB;   // fetch next ks0 -> X
        KSTEP(Ya0, Ya1, Yb0, Yb1, 3, nnoff + 32); SB;   // fetch next ks1 -> Y

        ssqa += __shfl_xor(ssqa, 16);  ssqa += __shfl_xor(ssqa, 32);
        ssqb += __shfl_xor(ssqb, 16);  ssqb += __shfl_xor(ssqb, 32);
        float inva = 1.0f / fmaxf(sqrtf(ssqa), EPSN);
        float invb = 1.0f / fmaxf(sqrtf(ssqb), EPSN);

        // C layout: col = lane&15 = local d-row; row(lq) = g*4+i (+16 for c1)
#pragma unroll
        for (int i = 0; i < 4; ++i) {
            rm0a[i] = fmaxf(rm0a[i], mk ? c0a[i] * inva : NEGV);
            rm1a[i] = fmaxf(rm1a[i], mk ? c1a[i] * inva : NEGV);
            rm0b[i] = fmaxf(rm0b[i], mk ? c0b[i] * invb : NEGV);
            rm1b[i] = fmaxf(rm1b[i], mk ? c1b[i] * invb : NEGV);
        }
        prow_a += 16 * DD;
        prow_b += 16 * DD;
    }
#undef KSTEP
#undef CVT2

    // max over the wave's 64 d-rows: reduce across the 16 cols (lane&15)
#pragma unroll
    for (int i = 0; i < 4; ++i) {
#pragma unroll
        for (int o = 1; o <= 8; o <<= 1) {
            rm0a[i] = fmaxf(rm0a[i], __shfl_xor(rm0a[i], o));
            rm1a[i] = fmaxf(rm1a[i], __shfl_xor(rm1a[i], o));
            rm0b[i] = fmaxf(rm0b[i], __shfl_xor(rm0b[i], o));
            rm1b[i] = fmaxf(rm1b[i], __shfl_xor(rm1b[i], o));
        }
    }
    if (r == 0) {
#pragma unroll
        for (int i = 0; i < 4; ++i) {
            wma[w][g * 4 + i]      = rm0a[i];
            wma[w][16 + g * 4 + i] = rm1a[i];
            wmb[w][g * 4 + i]      = rm0b[i];
            wmb[w][16 + g * 4 + i] = rm1b[i];
        }
    }
    __syncthreads();

    if (tid < 64) {   // lanes 0-31: cq, lanes 32-63: orig; l = lq
        int tau = tid >> 5, l = tid & 31;
        const float (*wm)[32] = tau ? wmb : wma;
        float v = fmaxf(fmaxf(wm[0][l], wm[1][l]),
                        fmaxf(wm[2][l], wm[3][l]));
#pragma unroll
        for (int o = 1; o <= 16; o <<= 1) v += __shfl_xor(v, o);
        if (l == 0)
            scores[tau * (Bq * Nn) + b * Nn + n] = v;
    }
}

// ---------------- Kernel 3: log_softmax + KL ----------------
__global__ void loss_k(const float* __restrict__ scores, float* __restrict__ out) {
    int tid = threadIdx.x;   // 128 threads, one per b
    const float* s = scores + tid * Nn;            // student (cq)
    const float* t = scores + Bq * Nn + tid * Nn;  // teacher (orig)
    float sv[Nn], tv[Nn];
#pragma unroll
    for (int n = 0; n < Nn; ++n) { sv[n] = s[n]; tv[n] = t[n]; }
    float ms = sv[0], mt = tv[0];
#pragma unroll
    for (int n = 1; n < Nn; ++n) { ms = fmaxf(ms, sv[n]); mt = fmaxf(mt, tv[n]); }
    float es = 0.0f, et = 0.0f;
#pragma unroll
    for (int n = 0; n < Nn; ++n) { es += expf(sv[n] - ms); et += expf(tv[n] - mt); }
    float lses = ms + logf(es);
    float lset = mt + logf(et);
    double kl = 0.0;
#pragma unroll
    for (int n = 0; n < Nn; ++n) {
        float lt = tv[n] - lset;
        float ls = sv[n] - lses;
        kl += (double)expf(lt) * ((double)lt - (double)ls);
    }
#pragma unroll
    for (int o = 32; o; o >>= 1) kl += __shfl_xor(kl, o);
    __shared__ double part[2];
    if ((tid & 63) == 0) part[tid >> 6] = kl;
    __syncthreads();
    if (tid == 0) out[0] = (float)((part[0] + part[1]) / (double)Bq);
}

extern "C" void kernel_launch(void* const* d_in, const int* in_sizes, int n_in,
                              void* d_out, int out_size, void* d_ws, size_t ws_size,
                              hipStream_t stream) {
    const float* q     = (const float*)d_in[0];
    const float* dcq   = (const float*)d_in[1];
    const float* dorig = (const float*)d_in[2];
    const int*   mask  = (const int*)d_in[3];
    // labels (d_in[4]) unused by the reference loss path

    unsigned short* qh = (unsigned short*)d_ws;                  // [B][32][128] bf16-hi, 1MB
    unsigned short* ql = qh + (size_t)Bq * LQ * DD;              // bf16-lo, 1MB
    float* scores      = (float*)(ql + (size_t)Bq * LQ * DD);    // [2][B][N], 8KB

    qnorm_k<<<(Bq * LQ) / 4, 256, 0, stream>>>(q, qh, ql);
    maxsim_k<<<Nn * Bq, 256, 0, stream>>>(dcq, dorig, mask, qh, ql, scores);
    loss_k<<<1, 128, 0, stream>>>(scores, (float*)d_out);
}

// Round 12
// 63.460 us; speedup vs baseline: 2.2686x; 1.0331x over previous
//
#include <hip/hip_runtime.h>
#include <math.h>

#define Bq 128
#define Nn 8
#define LQ 32
#define LD 256
#define DD 128
#define EPSN 1e-12f
#define NEGV (-9999.0f)

typedef __attribute__((ext_vector_type(8))) short short8v;
typedef __attribute__((ext_vector_type(4))) int   int4v;
typedef __attribute__((ext_vector_type(4))) float f32x4;

__device__ __forceinline__ unsigned bf16_rne_hibits(float x) {
    // returns (round-to-nearest-even bf16 of x) << 16, as f32 bit pattern
    unsigned u = __float_as_uint(x);
    return (u + 0x7FFFu + ((u >> 16) & 1u)) & 0xFFFF0000u;
}

// ---------------- Kernel 1: normalize q rows, emit bf16 hi/lo planes -------
// NEW (round 12): planes are written XOR-SWIZZLED within each 256B row:
// 16B chunk c -> c ^ (row&7). maxsim stages them into LDS linearly (layout
// preserved) and reads with the same XOR -> conflict-free ds_read_b128
// (unswizzled would be a 16-way bank conflict: lanes 0-15 same column).
__global__ __launch_bounds__(256) void qnorm_k(const float* __restrict__ q,
                                               unsigned short* __restrict__ qh,
                                               unsigned short* __restrict__ ql) {
    int row  = blockIdx.x * 4 + (threadIdx.x >> 6);   // 4096 rows = [B][LQ]
    int lane = threadIdx.x & 63;
    size_t base = (size_t)row * DD + lane * 2;
    float2 v = *reinterpret_cast<const float2*>(q + base);
    float ss = v.x * v.x + v.y * v.y;
#pragma unroll
    for (int o = 32; o; o >>= 1) ss += __shfl_xor(ss, o);
    float inv = 1.0f / fmaxf(sqrtf(ss), EPSN);
    float x0 = v.x * inv, x1 = v.y * inv;
    unsigned h0 = bf16_rne_hibits(x0), h1 = bf16_rne_hibits(x1);
    float l0 = x0 - __uint_as_float(h0);
    float l1 = x1 - __uint_as_float(h1);
    unsigned g0 = bf16_rne_hibits(l0), g1 = bf16_rne_hibits(l1);
    // swizzled element offset within the row (2 ushorts = 4B unit)
    unsigned swz = ((unsigned)(lane * 2)) ^ (((unsigned)row & 7u) << 3);
    *reinterpret_cast<unsigned*>(qh + (size_t)row * DD + swz) = (h0 >> 16) | h1;
    *reinterpret_cast<unsigned*>(ql + (size_t)row * DD + swz) = (g0 >> 16) | g1;
}

// ---------------- Kernel 2: MaxSim via MFMA, dual-tensor streams ----------
// Round-11 structure (65.6us): block = one (n,b), both tensors as two
// interleaved d-streams sharing A-fragments; distance-2 d prefetch.
// Round-12 changes:
//  - A-fragments (q hi/lo) come from LDS via swizzled ds_read_b128 instead
//    of per-KSTEP VMEM loads (round 11: 64 L2-latency A-loads/thread, 16KB
//    x 4 blocks = 64KB > 32KB L1 -> thrash; LDS read is lgkm-pipe, L1 freed
//    for the d-stream).
//  - CVT2 trunc split (round-8-verified: absmax 0.0), ~halves cvt VALU.
__global__ __launch_bounds__(256) void maxsim_k(const float* __restrict__ d_cq,
                                                const float* __restrict__ d_orig,
                                                const int* __restrict__ mask,
                                                const unsigned short* __restrict__ qh,
                                                const unsigned short* __restrict__ ql,
                                                float* __restrict__ scores) {
    __shared__ float4 qstage[1024];   // 16KB: [0,512)=qh plane, [512,1024)=ql
    __shared__ float wma[4][32];
    __shared__ float wmb[4][32];

    int nb = blockIdx.x;              // n*Bq + b, [0,1024)
    int b  = nb & 127;
    int n  = nb >> 7;

    int tid  = threadIdx.x;
    int w    = tid >> 6;              // wave id: d-rows [w*64, w*64+64)
    int lane = tid & 63;
    int r    = lane & 15;             // B-frag col / C col (local d-row)
    int g    = lane >> 4;             // k-group (8 elems each)

    {   // stage swizzled q planes -> LDS (linear copy preserves swizzle)
        const float4* srch = reinterpret_cast<const float4*>(qh + (size_t)b * LQ * DD);
        const float4* srcl = reinterpret_cast<const float4*>(ql + (size_t)b * LQ * DD);
        qstage[tid]       = srch[tid];
        qstage[tid + 256] = srch[tid + 256];
        qstage[tid + 512] = srcl[tid];
        qstage[tid + 768] = srcl[tid + 256];
    }
    __syncthreads();

    const unsigned short* qh_lds = reinterpret_cast<const unsigned short*>(qstage);
    const unsigned short* ql_lds = qh_lds + LQ * DD;
    unsigned swz8 = ((unsigned)r & 7u) << 3;   // read-side XOR (elem units)

    f32x4 rm0a = {NEGV, NEGV, NEGV, NEGV}, rm1a = {NEGV, NEGV, NEGV, NEGV};
    f32x4 rm0b = {NEGV, NEGV, NEGV, NEGV}, rm1b = {NEGV, NEGV, NEGV, NEGV};

#define SB __builtin_amdgcn_sched_barrier(0)

// truncation hi/lo split (round-8 verified): hi = bits, lo = x - hi, trunc lo
#define CVT2(DH, DL, W, X0, X1, SSQ)                                           \
    { unsigned u0 = __float_as_uint(X0), u1 = __float_as_uint(X1);             \
      DH[W] = (int)((u0 >> 16) | (u1 & 0xFFFF0000u));                          \
      float l0 = (X0) - __uint_as_float(u0 & 0xFFFF0000u);                     \
      float l1 = (X1) - __uint_as_float(u1 & 0xFFFF0000u);                     \
      DL[W] = (int)((__float_as_uint(l0) >> 16) |                              \
                    (__float_as_uint(l1) & 0xFFFF0000u));                      \
      SSQ += (X0)*(X0) + (X1)*(X1); }

// One k-slice, both streams. A-frags from LDS (swizzled); d buffers consumed
// then re-filled with PFOFF prefetch (WAR-safe by program order); 12 MFMAs.
#define KSTEP(CA0, CA1, CB0, CB1, KS, PFOFF)                                   \
    {                                                                          \
        unsigned aoff = (((unsigned)(KS) * 32u) + (unsigned)g * 8u) ^ swz8;    \
        short8v a0h = *reinterpret_cast<const short8v*>(qh_lds + r * DD + aoff);          \
        short8v a0l = *reinterpret_cast<const short8v*>(ql_lds + r * DD + aoff);          \
        short8v a1h = *reinterpret_cast<const short8v*>(qh_lds + (r + 16) * DD + aoff);   \
        short8v a1l = *reinterpret_cast<const short8v*>(ql_lds + (r + 16) * DD + aoff);   \
        int4v dhwa, dlwa, dhwb, dlwb;                                          \
        CVT2(dhwa, dlwa, 0, CA0.x, CA0.y, ssqa)                                \
        CVT2(dhwa, dlwa, 1, CA0.z, CA0.w, ssqa)                                \
        CVT2(dhwa, dlwa, 2, CA1.x, CA1.y, ssqa)                                \
        CVT2(dhwa, dlwa, 3, CA1.z, CA1.w, ssqa)                                \
        CA0 = *reinterpret_cast<const float4*>(prow_a + (PFOFF));              \
        CA1 = *reinterpret_cast<const float4*>(prow_a + (PFOFF) + 4);          \
        CVT2(dhwb, dlwb, 0, CB0.x, CB0.y, ssqb)                                \
        CVT2(dhwb, dlwb, 1, CB0.z, CB0.w, ssqb)                                \
        CVT2(dhwb, dlwb, 2, CB1.x, CB1.y, ssqb)                                \
        CVT2(dhwb, dlwb, 3, CB1.z, CB1.w, ssqb)                                \
        CB0 = *reinterpret_cast<const float4*>(prow_b + (PFOFF));              \
        CB1 = *reinterpret_cast<const float4*>(prow_b + (PFOFF) + 4);          \
        short8v dha = __builtin_bit_cast(short8v, dhwa);                       \
        short8v dla = __builtin_bit_cast(short8v, dlwa);                       \
        c0a = __builtin_amdgcn_mfma_f32_16x16x32_bf16(a0h, dha, c0a, 0, 0, 0); \
        c1a = __builtin_amdgcn_mfma_f32_16x16x32_bf16(a1h, dha, c1a, 0, 0, 0); \
        c0a = __builtin_amdgcn_mfma_f32_16x16x32_bf16(a0h, dla, c0a, 0, 0, 0); \
        c1a = __builtin_amdgcn_mfma_f32_16x16x32_bf16(a1h, dla, c1a, 0, 0, 0); \
        c0a = __builtin_amdgcn_mfma_f32_16x16x32_bf16(a0l, dha, c0a, 0, 0, 0); \
        c1a = __builtin_amdgcn_mfma_f32_16x16x32_bf16(a1l, dha, c1a, 0, 0, 0); \
        short8v dhb = __builtin_bit_cast(short8v, dhwb);                       \
        short8v dlb = __builtin_bit_cast(short8v, dlwb);                       \
        c0b = __builtin_amdgcn_mfma_f32_16x16x32_bf16(a0h, dhb, c0b, 0, 0, 0); \
        c1b = __builtin_amdgcn_mfma_f32_16x16x32_bf16(a1h, dhb, c1b, 0, 0, 0); \
        c0b = __builtin_amdgcn_mfma_f32_16x16x32_bf16(a0h, dlb, c0b, 0, 0, 0); \
        c1b = __builtin_amdgcn_mfma_f32_16x16x32_bf16(a1h, dlb, c1b, 0, 0, 0); \
        c0b = __builtin_amdgcn_mfma_f32_16x16x32_bf16(a0l, dhb, c0b, 0, 0, 0); \
        c1b = __builtin_amdgcn_mfma_f32_16x16x32_bf16(a1l, dhb, c1b, 0, 0, 0); \
    }

    // per-lane row pointers for the two streams (same geometry, two tensors)
    const float* prow_a = d_cq   + (size_t)nb * (LD * DD) + (size_t)(w * 64 + r) * DD + g * 8;
    const float* prow_b = d_orig + (size_t)nb * (LD * DD) + (size_t)(w * 64 + r) * DD + g * 8;

    // steady-state: X holds ks0, Y holds ks1 at nt-loop top (both streams)
    float4 Xa0 = *reinterpret_cast<const float4*>(prow_a);
    float4 Xa1 = *reinterpret_cast<const float4*>(prow_a + 4);
    float4 Xb0 = *reinterpret_cast<const float4*>(prow_b);
    float4 Xb1 = *reinterpret_cast<const float4*>(prow_b + 4);
    float4 Ya0 = *reinterpret_cast<const float4*>(prow_a + 32);
    float4 Ya1 = *reinterpret_cast<const float4*>(prow_a + 36);
    float4 Yb0 = *reinterpret_cast<const float4*>(prow_b + 32);
    float4 Yb1 = *reinterpret_cast<const float4*>(prow_b + 36);

#pragma unroll 1
    for (int nt = 0; nt < 4; ++nt) {
        int drow = w * 64 + nt * 16 + r;

        f32x4 c0a = {0.f, 0.f, 0.f, 0.f}, c1a = {0.f, 0.f, 0.f, 0.f};
        f32x4 c0b = {0.f, 0.f, 0.f, 0.f}, c1b = {0.f, 0.f, 0.f, 0.f};
        float ssqa = 0.0f, ssqb = 0.0f;

        int mk = mask[(size_t)nb * LD + drow];    // shared by both tensors
        int nnoff = (nt < 3) ? 2048 : 0;          // next-nt (16 rows) or clamp

        KSTEP(Xa0, Xa1, Xb0, Xb1, 0, 64);         SB;   // fetch ks2 -> X
        KSTEP(Ya0, Ya1, Yb0, Yb1, 1, 96);         SB;   // fetch ks3 -> Y
        KSTEP(Xa0, Xa1, Xb0, Xb1, 2, nnoff);      SB;   // fetch next ks0 -> X
        KSTEP(Ya0, Ya1, Yb0, Yb1, 3, nnoff + 32); SB;   // fetch next ks1 -> Y

        ssqa += __shfl_xor(ssqa, 16);  ssqa += __shfl_xor(ssqa, 32);
        ssqb += __shfl_xor(ssqb, 16);  ssqb += __shfl_xor(ssqb, 32);
        float inva = 1.0f / fmaxf(sqrtf(ssqa), EPSN);
        float invb = 1.0f / fmaxf(sqrtf(ssqb), EPSN);

        // C layout: col = lane&15 = local d-row; row(lq) = g*4+i (+16 for c1)
#pragma unroll
        for (int i = 0; i < 4; ++i) {
            rm0a[i] = fmaxf(rm0a[i], mk ? c0a[i] * inva : NEGV);
            rm1a[i] = fmaxf(rm1a[i], mk ? c1a[i] * inva : NEGV);
            rm0b[i] = fmaxf(rm0b[i], mk ? c0b[i] * invb : NEGV);
            rm1b[i] = fmaxf(rm1b[i], mk ? c1b[i] * invb : NEGV);
        }
        prow_a += 16 * DD;
        prow_b += 16 * DD;
    }
#undef KSTEP
#undef CVT2

    // max over the wave's 64 d-rows: reduce across the 16 cols (lane&15)
#pragma unroll
    for (int i = 0; i < 4; ++i) {
#pragma unroll
        for (int o = 1; o <= 8; o <<= 1) {
            rm0a[i] = fmaxf(rm0a[i], __shfl_xor(rm0a[i], o));
            rm1a[i] = fmaxf(rm1a[i], __shfl_xor(rm1a[i], o));
            rm0b[i] = fmaxf(rm0b[i], __shfl_xor(rm0b[i], o));
            rm1b[i] = fmaxf(rm1b[i], __shfl_xor(rm1b[i], o));
        }
    }
    if (r == 0) {
#pragma unroll
        for (int i = 0; i < 4; ++i) {
            wma[w][g * 4 + i]      = rm0a[i];
            wma[w][16 + g * 4 + i] = rm1a[i];
            wmb[w][g * 4 + i]      = rm0b[i];
            wmb[w][16 + g * 4 + i] = rm1b[i];
        }
    }
    __syncthreads();

    if (tid < 64) {   // lanes 0-31: cq, lanes 32-63: orig; l = lq
        int tau = tid >> 5, l = tid & 31;
        const float (*wm)[32] = tau ? wmb : wma;
        float v = fmaxf(fmaxf(wm[0][l], wm[1][l]),
                        fmaxf(wm[2][l], wm[3][l]));
#pragma unroll
        for (int o = 1; o <= 16; o <<= 1) v += __shfl_xor(v, o);
        if (l == 0)
            scores[tau * (Bq * Nn) + b * Nn + n] = v;
    }
}

// ---------------- Kernel 3: log_softmax + KL ----------------
__global__ void loss_k(const float* __restrict__ scores, float* __restrict__ out) {
    int tid = threadIdx.x;   // 128 threads, one per b
    const float* s = scores + tid * Nn;            // student (cq)
    const float* t = scores + Bq * Nn + tid * Nn;  // teacher (orig)
    float sv[Nn], tv[Nn];
#pragma unroll
    for (int n = 0; n < Nn; ++n) { sv[n] = s[n]; tv[n] = t[n]; }
    float ms = sv[0], mt = tv[0];
#pragma unroll
    for (int n = 1; n < Nn; ++n) { ms = fmaxf(ms, sv[n]); mt = fmaxf(mt, tv[n]); }
    float es = 0.0f, et = 0.0f;
#pragma unroll
    for (int n = 0; n < Nn; ++n) { es += expf(sv[n] - ms); et += expf(tv[n] - mt); }
    float lses = ms + logf(es);
    float lset = mt + logf(et);
    double kl = 0.0;
#pragma unroll
    for (int n = 0; n < Nn; ++n) {
        float lt = tv[n] - lset;
        float ls = sv[n] - lses;
        kl += (double)expf(lt) * ((double)lt - (double)ls);
    }
#pragma unroll
    for (int o = 32; o; o >>= 1) kl += __shfl_xor(kl, o);
    __shared__ double part[2];
    if ((tid & 63) == 0) part[tid >> 6] = kl;
    __syncthreads();
    if (tid == 0) out[0] = (float)((part[0] + part[1]) / (double)Bq);
}

extern "C" void kernel_launch(void* const* d_in, const int* in_sizes, int n_in,
                              void* d_out, int out_size, void* d_ws, size_t ws_size,
                              hipStream_t stream) {
    const float* q     = (const float*)d_in[0];
    const float* dcq   = (const float*)d_in[1];
    const float* dorig = (const float*)d_in[2];
    const int*   mask  = (const int*)d_in[3];
    // labels (d_in[4]) unused by the reference loss path

    unsigned short* qh = (unsigned short*)d_ws;                  // [B][32][128] bf16-hi (swizzled rows), 1MB
    unsigned short* ql = qh + (size_t)Bq * LQ * DD;              // bf16-lo (swizzled rows), 1MB
    float* scores      = (float*)(ql + (size_t)Bq * LQ * DD);    // [2][B][N], 8KB

    qnorm_k<<<(Bq * LQ) / 4, 256, 0, stream>>>(q, qh, ql);
    maxsim_k<<<Nn * Bq, 256, 0, stream>>>(dcq, dorig, mask, qh, ql, scores);
    loss_k<<<1, 128, 0, stream>>>(scores, (float*)d_out);
}